// Round 2
// baseline (226.912 us; speedup 1.0000x reference)
//
#include <hip/hip_runtime.h>

// Chamfer distance K=1 NN, both directions. N=4, P1=P2=8192, D=3, fp32.
//
// Correctness strategy: bitwise-replicate numpy's fp32 arithmetic
//   d2 = (||p||^2 + ||q||^2) - 2.0 * (((px*qx) + (py*qy)) + (pz*qz))
// with sequential rounding and NO fma contraction, so argmin (first-index
// tie-break) matches np.argmin exactly.
//
// Perf strategy:
//   prep: float4 [x, y, z, ||pt||^2] for all 65536 points in d_ws.
//   main: 64 query pts/block x 4 waves (4 target segments of 2048);
//     targets streamed via wave-uniform (scalar) loads; per-8 min tree +
//     winning-block tracking; exact index via 8-elem descending rescan;
//     cross-segment LDS reduce with smallest-index tie-break.

#define SEG 2048
#define UNROLL 8

__global__ __launch_bounds__(256) void chamfer_prep(const float* __restrict__ x,
                                                    const float* __restrict__ y,
                                                    float4* __restrict__ ws) {
#pragma clang fp contract(off)
    int i = blockIdx.x * 256 + threadIdx.x;     // 0..65535
    const float* src = (i < 32768) ? x : y;
    int j = (i < 32768) ? i : (i - 32768);
    float a = src[j * 3 + 0];
    float b = src[j * 3 + 1];
    float c = src[j * 3 + 2];
    float s = ((a * a) + (b * b)) + (c * c);    // np.sum(a*a, -1) rounding order
    ws[i] = make_float4(a, b, c, s);
}

__global__ __launch_bounds__(256) void chamfer_nn(const float4* __restrict__ ws,
                                                  float* __restrict__ out) {
#pragma clang fp contract(off)
    int b   = blockIdx.x;          // 0..1023
    int dir = b >> 9;              // 0: x->y, 1: y->x
    int r   = b & 511;
    int n   = r >> 7;              // batch 0..3
    int p0  = (r & 127) << 6;      // 64 query points per block
    int lane = threadIdx.x & 63;
    int seg  = threadIdx.x >> 6;   // wave id = target segment 0..3
    int p    = p0 + lane;

    const float4* qarr = ws + (dir == 0 ? 0 : 32768) + n * 8192;
    const float4* tgt  = ws + (dir == 0 ? 32768 : 0) + n * 8192;

    float4 qp = qarr[p];
    float px = qp.x, py = qp.y, pz = qp.z, sp = qp.w;

    float best = __builtin_inff();
    int bblk = 0;
    int qbase = seg * SEG;

    for (int blk = 0; blk < SEG / UNROLL; ++blk) {
        int q0 = __builtin_amdgcn_readfirstlane(qbase + blk * UNROLL);
        float t[UNROLL];
#pragma unroll
        for (int j = 0; j < UNROLL; ++j) {
            float4 q = tgt[q0 + j];
            float dot = ((px * q.x) + (py * q.y)) + (pz * q.z);
            float t1  = sp + q.w;
            t[j] = t1 - (2.0f * dot);           // exact np rounding order
        }
        float m01 = fminf(t[0], t[1]);
        float m23 = fminf(t[2], t[3]);
        float m45 = fminf(t[4], t[5]);
        float m67 = fminf(t[6], t[7]);
        float m0123 = fminf(m01, m23);
        float m4567 = fminf(m45, m67);
        float m = fminf(m0123, m4567);
        if (m < best) { best = m; bblk = blk; }   // strict < keeps earliest block
    }

    // rescan winning block; recompute is bitwise-identical, so == is exact.
    int q0 = qbase + bblk * UNROLL;
    int idx = q0;
#pragma unroll
    for (int j = UNROLL - 1; j >= 0; --j) {   // descending: final write = smallest j
        float4 q = tgt[q0 + j];
        float dot = ((px * q.x) + (py * q.y)) + (pz * q.z);
        float t1  = sp + q.w;
        float t = t1 - (2.0f * dot);
        if (t == best) idx = q0 + j;
    }

    // cross-segment reduction, smallest-index tie-break
    __shared__ float sval[256];
    __shared__ int   sidx[256];
    sval[threadIdx.x] = best;
    sidx[threadIdx.x] = idx;
    __syncthreads();

    if (threadIdx.x < 64) {
        float bv = sval[threadIdx.x];
        int   bi = sidx[threadIdx.x];
#pragma unroll
        for (int w = 1; w < 4; ++w) {
            float v  = sval[w * 64 + threadIdx.x];
            int   i2 = sidx[w * 64 + threadIdx.x];
            if (v < bv || (v == bv && i2 < bi)) { bv = v; bi = i2; }
        }
        // out layout: cham_x[32768] cham_y[32768] idx_x[32768] idx_y[32768]
        int distoff = (dir == 0) ? 0     : 32768;
        int idxoff  = (dir == 0) ? 65536 : 98304;
        int o = n * 8192 + p0 + threadIdx.x;
        out[distoff + o] = bv;
        out[idxoff + o]  = (float)bi;
    }
}

extern "C" void kernel_launch(void* const* d_in, const int* in_sizes, int n_in,
                              void* d_out, int out_size, void* d_ws, size_t ws_size,
                              hipStream_t stream) {
    const float* x = (const float*)d_in[0];
    const float* y = (const float*)d_in[1];
    float4* ws = (float4*)d_ws;
    float* out = (float*)d_out;

    chamfer_prep<<<256, 256, 0, stream>>>(x, y, ws);
    chamfer_nn<<<1024, 256, 0, stream>>>(ws, out);
}

// Round 3
// 146.985 us; speedup vs baseline: 1.5438x; 1.5438x over previous
//
#include <hip/hip_runtime.h>

// Chamfer distance K=1 NN, both directions. N=4, P1=P2=8192, D=3, fp32.
//
// Numerics: bitwise-replicate numpy fp32:
//   d2 = (sp + sq) - 2.0f * (((px*qx) + (py*qy)) + (pz*qz))
// fp contract OFF everywhere; the final mul+sub is folded to fma(-2,dot,t1)
// which is bitwise identical because multiplication by 2.0 is exact.
// Packed v2f32 ops (v_pk_mul/add/fma_f32) round identically per element.
//
// Structure:
//   prep : SoA [X|Y|Z|S] (65536 each) in ws; S = ((x*x)+(y*y))+(z*z).
//   main : 2048 blocks x 256 thr. block = 64 queries x 4 waves; each wave
//          scans 1024 targets (block covers a 4096-target half) with
//          wave-uniform scalar loads (SoA pairs -> packed operands),
//          16 targets/iter, per-16 min tree + winning-iter tracking,
//          exact index via descending scalar rescan (bitwise-identical),
//          LDS reduce across waves -> per-block partial (val, local idx).
//   merge: 65536 thr, combine the 2 half-block partials per query
//          (strict < : ties keep half 0 = smaller indices), write out.

typedef float v2f __attribute__((ext_vector_type(2)));

#define NPTS 32768
#define TSEG 1024
#define UN 16

// ws float offsets
#define OFF_X 0
#define OFF_Y 65536
#define OFF_Z 131072
#define OFF_S 196608
#define OFF_PV 262144
#define OFF_PI 393216

__global__ __launch_bounds__(256) void chamfer_prep(const float* __restrict__ x,
                                                    const float* __restrict__ y,
                                                    float* __restrict__ ws) {
#pragma clang fp contract(off)
    int i = blockIdx.x * 256 + threadIdx.x;     // 0..65535
    const float* src = (i < NPTS) ? x : y;
    int j = (i < NPTS) ? i : (i - NPTS);
    float a = src[j * 3 + 0];
    float b = src[j * 3 + 1];
    float c = src[j * 3 + 2];
    ws[OFF_X + i] = a;
    ws[OFF_Y + i] = b;
    ws[OFF_Z + i] = c;
    ws[OFF_S + i] = ((a * a) + (b * b)) + (c * c);
}

__global__ __launch_bounds__(256) void chamfer_nn(const float* __restrict__ ws,
                                                  float* __restrict__ pv,
                                                  int* __restrict__ pix) {
#pragma clang fp contract(off)
    int b   = blockIdx.x;            // 0..2047
    int dir = b >> 10;               // 0: x->y, 1: y->x
    int r   = b & 1023;
    int n   = r >> 8;                // batch
    int r2  = r & 255;
    int qg  = r2 >> 1;               // query group of 64 (0..127)
    int sh  = r2 & 1;                // target half (0..1)
    int lane = threadIdx.x & 63;
    int seg  = threadIdx.x >> 6;     // wave id 0..3

    const float* X = ws + OFF_X;
    const float* Y = ws + OFF_Y;
    const float* Z = ws + OFF_Z;
    const float* S = ws + OFF_S;

    int qidx   = (dir ? NPTS : 0) + n * 8192 + qg * 64 + lane;
    int tcbase = (dir ? 0 : NPTS) + n * 8192;          // target cloud base
    int tbase  = tcbase + (sh * 4 + seg) * TSEG;       // this wave's segment

    float px = X[qidx], py = Y[qidx], pz = Z[qidx], sp = S[qidx];

    const v2f* X2 = (const v2f*)X;
    const v2f* Y2 = (const v2f*)Y;
    const v2f* Z2 = (const v2f*)Z;
    const v2f* S2 = (const v2f*)S;

    float best = __builtin_inff();
    int bblk = 0;

    for (int blk = 0; blk < TSEG / UN; ++blk) {
        int t0 = __builtin_amdgcn_readfirstlane(tbase + blk * UN);
        int p0 = t0 >> 1;                               // v2f pair index
        float pm[UN / 2];
#pragma unroll
        for (int i = 0; i < UN / 2; ++i) {
            v2f xv = X2[p0 + i];
            v2f yv = Y2[p0 + i];
            v2f zv = Z2[p0 + i];
            v2f sv = S2[p0 + i];
            v2f dot = ((xv * px) + (yv * py)) + (zv * pz);
            v2f t1  = sp + sv;
            v2f m2  = {-2.0f, -2.0f};
            v2f t   = __builtin_elementwise_fma(m2, dot, t1);
            pm[i] = fminf(t.x, t.y);
        }
        float m01 = fminf(pm[0], pm[1]);
        float m23 = fminf(pm[2], pm[3]);
        float m45 = fminf(pm[4], pm[5]);
        float m67 = fminf(pm[6], pm[7]);
        float m = fminf(fminf(m01, m23), fminf(m45, m67));
        if (m < best) { best = m; bblk = blk; }   // strict <: earliest iter wins
    }

    // rescan winning 16-target group; scalar ops round identically to packed,
    // so == against best is exact. Descending j: final hit = smallest index.
    int t0 = tbase + bblk * UN;
    int idx = t0;
#pragma unroll
    for (int j = UN - 1; j >= 0; --j) {
        float qx = X[t0 + j], qy = Y[t0 + j], qz = Z[t0 + j], qs = S[t0 + j];
        float dot = ((px * qx) + (py * qy)) + (pz * qz);
        float t1  = sp + qs;
        float t   = fmaf(-2.0f, dot, t1);
        if (t == best) idx = t0 + j;
    }

    // cross-wave reduction (4 waves = 4 contiguous segments of this half)
    __shared__ float sval[256];
    __shared__ int   sidx[256];
    sval[threadIdx.x] = best;
    sidx[threadIdx.x] = idx;
    __syncthreads();

    if (threadIdx.x < 64) {
        float bv = sval[threadIdx.x];
        int   bi = sidx[threadIdx.x];
#pragma unroll
        for (int w = 1; w < 4; ++w) {
            float v  = sval[w * 64 + threadIdx.x];
            int   i2 = sidx[w * 64 + threadIdx.x];
            if (v < bv || (v == bv && i2 < bi)) { bv = v; bi = i2; }
        }
        pv[b * 64 + threadIdx.x]  = bv;
        pix[b * 64 + threadIdx.x] = bi - tcbase;   // local target index 0..8191
    }
}

__global__ __launch_bounds__(256) void chamfer_merge(const float* __restrict__ pv,
                                                     const int* __restrict__ pix,
                                                     float* __restrict__ out) {
    int g = blockIdx.x * 256 + threadIdx.x;   // 0..65535
    int dir = g >> 15;
    int w   = g & 32767;
    int n   = w >> 13;
    int v   = w & 8191;
    int qg  = v >> 6;
    int q   = v & 63;

    int b0 = ((dir * 4 + n) * 128 + qg) * 2;  // main-kernel block id, sh=0
    int i0 = b0 * 64 + q;
    int i1 = i0 + 64;                          // sh=1 partial

    float v0 = pv[i0], v1 = pv[i1];
    int   j0 = pix[i0], j1 = pix[i1];
    float bv; int bi;
    if (v1 < v0) { bv = v1; bi = j1; }         // ties -> half 0 (smaller idx)
    else         { bv = v0; bi = j0; }

    int o = n * 8192 + qg * 64 + q;
    int distoff = dir ? 32768 : 0;
    int idxoff  = dir ? 98304 : 65536;
    out[distoff + o] = bv;
    out[idxoff + o]  = (float)bi;
}

extern "C" void kernel_launch(void* const* d_in, const int* in_sizes, int n_in,
                              void* d_out, int out_size, void* d_ws, size_t ws_size,
                              hipStream_t stream) {
    const float* x = (const float*)d_in[0];
    const float* y = (const float*)d_in[1];
    float* ws  = (float*)d_ws;
    float* out = (float*)d_out;

    chamfer_prep<<<256, 256, 0, stream>>>(x, y, ws);
    chamfer_nn<<<2048, 256, 0, stream>>>(ws, ws + OFF_PV, (int*)(ws + OFF_PI));
    chamfer_merge<<<256, 256, 0, stream>>>(ws + OFF_PV, (const int*)(ws + OFF_PI), out);
}